// Round 9
// baseline (53.622 us; speedup 1.0000x reference)
//
#include <hip/hip_runtime.h>
#include <hip/hip_bf16.h>

#define B_      4
#define L_      2048
#define NE_     768
#define NOUT_   256     // N_BINS * N_HIDDEN
#define NH_     32
#define NB_     8
#define V_      64
#define VOCAB_  1270
#define NC_     32          // chunks per batch row
#define CS_     64          // L_/NC_
#define BM_     32
#define BK_     32
#define NT_     24          // NE_/BK_
#define DEPTH_  4
#define NROWS_  8192
#define GRID_MAIN_ 256
#define INV_M_  (1.0f / 4194304.0f) // 1/(B*L*NB*V)
#define INF_    0x7FFFFFFF

typedef float f32x4 __attribute__((ext_vector_type(4)));
typedef short s16x8 __attribute__((ext_vector_type(8)));

__device__ __forceinline__ unsigned short f2bf(float x) {
    union { float f; unsigned u; } c; c.f = x;
    unsigned u = c.u;
    return (unsigned short)((u + 0x7fffu + ((u >> 16) & 1u)) >> 16);   // RNE
}

__device__ __forceinline__ s16x8 cvt8(float4 a, float4 b) {
    union { __hip_bfloat162 h2[4]; s16x8 v; } r;
    r.h2[0] = __float22bfloat162_rn(make_float2(a.x, a.y));
    r.h2[1] = __float22bfloat162_rn(make_float2(a.z, a.w));
    r.h2[2] = __float22bfloat162_rn(make_float2(b.x, b.y));
    r.h2[3] = __float22bfloat162_rn(make_float2(b.z, b.w));
    return r.v;
}

// ---------------- workspace layout (bytes) ----------------
// [0     , 32768 ) mt        int[B*L]
// [32768 , 65536 ) firstocc  int[B*NC*V]
// [65536 , 458752) W1t       bf16[256][768]
// [458752, 462848) W2t       bf16[64][32]
// [462848, 464896) partials  float[512] (256 used)
// [464896, 464900) cnt       unsigned

// ---- kernel 1: blocks 0..47 W1t transpose; block 48 W2t + cnt reset;
//                blocks 49..80 mt + firstocc (4 chunks per block)
__global__ void __launch_bounds__(256)
k_prep(const int* __restrict__ task_tokens, const float* __restrict__ W1,
       const float* __restrict__ W2, const int* __restrict__ targets,
       short* __restrict__ W1t, short* __restrict__ W2t,
       int* __restrict__ mt, int* __restrict__ firstocc, unsigned* __restrict__ cnt) {
    __shared__ float tl[64][67];
    __shared__ int   stask[V_];
    __shared__ int   smt[4][CS_];
    const int tid = threadIdx.x;

    if (blockIdx.x < 48) {
        const int tIdx = blockIdx.x;
        const int kt = (tIdx % 12) * 64;
        const int ct = (tIdx / 12) * 64;
        #pragma unroll
        for (int p = 0; p < 4; ++p) {
            int kk = (tid >> 4) + p * 16;
            int cc = (tid & 15) * 4;
            float4 v = *reinterpret_cast<const float4*>(&W1[(kt + kk) * NOUT_ + ct + cc]);
            tl[kk][cc] = v.x; tl[kk][cc + 1] = v.y; tl[kk][cc + 2] = v.z; tl[kk][cc + 3] = v.w;
        }
        __syncthreads();
        #pragma unroll
        for (int p = 0; p < 8; ++p) {
            int oc  = (tid >> 5) + p * 8;
            int ok2 = (tid & 31) * 2;
            unsigned pk = ((unsigned)f2bf(tl[ok2 + 1][oc]) << 16) | f2bf(tl[ok2][oc]);
            *reinterpret_cast<unsigned*>(&W1t[(ct + oc) * NE_ + kt + ok2]) = pk;
        }
        return;
    }
    if (blockIdx.x == 48) {
        if (tid == 0) cnt[0] = 0u;
        #pragma unroll
        for (int q = 0; q < 8; ++q) {
            int i = tid + q * 256;
            int col = i >> 5, j = i & 31;
            W2t[col * NH_ + j] = (short)f2bf(W2[j * V_ + col]);
        }
        return;
    }
    // ---- occ blocks: 4 chunks each ----
    if (tid < V_) stask[tid] = task_tokens[tid];
    __syncthreads();
    const int gi = tid >> 6;
    const int v  = tid & 63;
    const int g  = (blockIdx.x - 49) * 4 + gi;
    const int b  = g >> 5, c = g & 31;
    int t = targets[b * L_ + c * CS_ + v];
    int mval = -1;
    #pragma unroll
    for (int j = 0; j < V_; ++j)
        mval = (stask[j] == t) ? j : mval;
    mt[b * L_ + c * CS_ + v] = mval;
    smt[gi][v] = mval;                          // wave-local
    int first = INF_;
    for (int j = CS_ - 1; j >= 0; --j)
        if (smt[gi][j] == v) first = c * CS_ + j;
    firstocc[(b * NC_ + c) * V_ + v] = first;
}

// ---- kernel 2: fused tte + register-pipelined LDS-free bf16 MFMA GEMM1(32x256)
//                + MFMA GEMM2 + loss + last-block final reduce
__global__ void __launch_bounds__(512, 2)
k_main(const float* __restrict__ h, const float* __restrict__ age,
       const float* __restrict__ targets_age,
       const int* __restrict__ mt, const int* __restrict__ firstocc,
       const short* __restrict__ W1t, const short* __restrict__ W2t,
       const float* __restrict__ time_bins, float* __restrict__ partials,
       unsigned* __restrict__ cnt, float* __restrict__ out) {
    __shared__ __align__(16) short sH[NB_][BM_][40];   // hh bf16, A-frag layout
    __shared__ __align__(16) short sW2[V_][40];
    __shared__ float stte[BM_][66];
    __shared__ int   sminI[8][V_];
    __shared__ int   smt[CS_];
    __shared__ float sage[BM_];
    __shared__ float sred[8];
    __shared__ float s2[4];
    __shared__ int   sLast;

    const int tid = threadIdx.x;
    const int w   = tid >> 6;
    const int l   = tid & 63;
    const int l15 = l & 15;
    const int l4  = l >> 4;
    const int r0  = blockIdx.x * BM_;
    const int b   = r0 >> 11;
    const int pos0 = r0 & (L_ - 1);
    const int c    = pos0 >> 6;           // chunk
    const int off  = pos0 & 63;           // 0 or 32

    // ---- per-lane direct fragment bases ----
    const float* hA0 = &h[(r0 + l15) * NE_];
    const float* hA1 = &h[(r0 + 16 + l15) * NE_];
    const short* wB0 = &W1t[(w * 32 + l15) * NE_];
    const short* wB1 = &W1t[(w * 32 + 16 + l15) * NE_];
    const int kb = l4 * 8;

    // ---- warmup: tiles 0..3 into slots 0..3 (in flight through prologue) ----
    float4 a0[DEPTH_], a1[DEPTH_], a2s[DEPTH_], a3[DEPTH_];
    s16x8  b0[DEPTH_], b1[DEPTH_];
    #pragma unroll
    for (int p = 0; p < DEPTH_; ++p) {
        const int kk = p * BK_ + kb;
        a0[p]  = *(const float4*)&hA0[kk];
        a1[p]  = *(const float4*)&hA0[kk + 4];
        a2s[p] = *(const float4*)&hA1[kk];
        a3[p]  = *(const float4*)&hA1[kk + 4];
        b0[p]  = *(const s16x8*)&wB0[kk];
        b1[p]  = *(const s16x8*)&wB1[kk];
    }

    // ---- stage small stuff ----
    if (tid < CS_)  smt[tid]  = mt[b * L_ + c * CS_ + tid];
    if (tid < BM_)  sage[tid] = age[r0 + tid];
    if (tid < 256) {
        int col = tid >> 2, ch = tid & 3;
        *(s16x8*)&sW2[col][ch * 8] = *(const s16x8*)&W2t[col * NH_ + ch * 8];
    }

    // ---- wave-parallel suffix-min over later chunks ----
    {
        int cur = INF_;
        #pragma unroll
        for (int k = 0; k < 4; ++k) {
            int cc = c + 1 + w + k * 8;
            if (cc < NC_) cur = min(cur, firstocc[(b * NC_ + cc) * V_ + l]);
        }
        sminI[w][l] = cur;
    }
    __syncthreads();

    // ---- inline tte scan (wave w owns rows w*4..w*4+3) ----
    {
        const int v  = l;
        const int rg = w;
        int cur = INF_;
        #pragma unroll
        for (int ww = 0; ww < 8; ++ww) cur = min(cur, sminI[ww][v]);
        int* stteI = (int*)stte;
        const int jmin = off + rg * 4;
        for (int j = CS_ - 1; j >= jmin; --j) {
            if (smt[j] == v) cur = c * CS_ + j;
            int br = j - off;
            if ((br >> 2) == rg) stteI[br * 66 + v] = cur;
        }
        #pragma unroll
        for (int jr = 0; jr < 4; ++jr) {
            int br  = rg * 4 + jr;
            int tok = stteI[br * 66 + v];
            float val = -1.0f;
            if (tok != INF_) val = targets_age[b * L_ + tok] - sage[br];
            stte[br][v] = val;
        }
    }

    // ---- GEMM1: LDS-free, barrier-free, depth-4 register-pipelined K loop ----
    f32x4 acc[2][2] = {};
    #pragma unroll
    for (int t = 0; t < NT_; ++t) {
        const int sl = t & 3;
        s16x8 af0 = cvt8(a0[sl], a1[sl]);
        s16x8 af1 = cvt8(a2s[sl], a3[sl]);
        s16x8 bf0 = b0[sl];
        s16x8 bf1 = b1[sl];
        if (t + DEPTH_ < NT_) {
            const int kk = (t + DEPTH_) * BK_ + kb;
            a0[sl]  = *(const float4*)&hA0[kk];
            a1[sl]  = *(const float4*)&hA0[kk + 4];
            a2s[sl] = *(const float4*)&hA1[kk];
            a3[sl]  = *(const float4*)&hA1[kk + 4];
            b0[sl]  = *(const s16x8*)&wB0[kk];
            b1[sl]  = *(const s16x8*)&wB1[kk];
        }
        acc[0][0] = __builtin_amdgcn_mfma_f32_16x16x32_bf16(af0, bf0, acc[0][0], 0, 0, 0);
        acc[0][1] = __builtin_amdgcn_mfma_f32_16x16x32_bf16(af0, bf1, acc[0][1], 0, 0, 0);
        acc[1][0] = __builtin_amdgcn_mfma_f32_16x16x32_bf16(af1, bf0, acc[1][0], 0, 0, 0);
        acc[1][1] = __builtin_amdgcn_mfma_f32_16x16x32_bf16(af1, bf1, acc[1][1], 0, 0, 0);
    }

    // ---- hh -> sH; wave w owns bin n = w (its 32-col slice) ----
    #pragma unroll
    for (int rf2 = 0; rf2 < 2; ++rf2)
        #pragma unroll
        for (int cfg = 0; cfg < 2; ++cfg) {
            int jj = cfg * 16 + l15;
            #pragma unroll
            for (int jr = 0; jr < 4; ++jr)
                sH[w][rf2 * 16 + l4 * 4 + jr][jj] = (short)f2bf(acc[rf2][cfg][jr]);
        }
    __syncthreads();

    // ---- GEMM2 + loss: wave owns (rf = w&1, cf = w>>1), loops all 8 bins ----
    const int rf = w & 1;
    const int cf = w >> 1;
    const int v  = cf * 16 + l15;
    s16x8 b2 = *(const s16x8*)&sW2[v][l4 * 8];

    float tb[NB_ + 1];
    #pragma unroll
    for (int n = 0; n <= NB_; ++n) tb[n] = time_bins[n];

    float tva[4], lcv[4];
    const float lastTA = targets_age[b * L_ + (L_ - 1)];
    #pragma unroll
    for (int jr = 0; jr < 4; ++jr) {
        int br = rf * 16 + l4 * 4 + jr;
        tva[jr] = stte[br][v];
        lcv[jr] = lastTA - sage[br];
    }

    float part = 0.0f;
    const f32x4 zero = {};
    #pragma unroll
    for (int n = 0; n < NB_; ++n) {
        s16x8 a2 = *(const s16x8*)&sH[n][rf * 16 + l15][l4 * 8];
        f32x4 c2 = __builtin_amdgcn_mfma_f32_16x16x32_bf16(a2, b2, zero, 0, 0, 0);
        float sn = tb[n], en = tb[n + 1], wn = en - sn;
        #pragma unroll
        for (int jr = 0; jr < 4; ++jr) {
            float ll = c2[jr];
            float ex = __expf(ll);
            float tv = tva[jr];
            bool occ = (tv > sn) && (tv <= en);
            float cn = fminf(fmaxf(lcv[jr], 0.0f), wn);
            part += ex * (occ ? tv : cn) - (occ ? ll : 0.0f);
        }
    }

    #pragma unroll
    for (int offs = 32; offs > 0; offs >>= 1) part += __shfl_xor(part, offs);
    if (l == 0) sred[w] = part;
    __syncthreads();
    if (tid == 0) {
        float s = 0.0f;
        #pragma unroll
        for (int i = 0; i < 8; ++i) s += sred[i];
        __hip_atomic_store(&partials[blockIdx.x], s, __ATOMIC_RELEASE, __HIP_MEMORY_SCOPE_AGENT);
        unsigned old = __hip_atomic_fetch_add(cnt, 1u, __ATOMIC_ACQ_REL, __HIP_MEMORY_SCOPE_AGENT);
        sLast = (old == GRID_MAIN_ - 1u);
    }
    __syncthreads();
    if (sLast) {
        float x = 0.0f;
        if (tid < 256)
            x = __hip_atomic_load(&partials[tid], __ATOMIC_RELAXED, __HIP_MEMORY_SCOPE_AGENT);
        #pragma unroll
        for (int o = 32; o > 0; o >>= 1) x += __shfl_xor(x, o);
        if (tid < 256 && (tid & 63) == 0) s2[tid >> 6] = x;
        __syncthreads();
        if (tid == 0) out[0] = (s2[0] + s2[1] + s2[2] + s2[3]) * INV_M_;
    }
}

extern "C" void kernel_launch(void* const* d_in, const int* in_sizes, int n_in,
                              void* d_out, int out_size, void* d_ws, size_t ws_size,
                              hipStream_t stream) {
    const float* h           = (const float*)d_in[0];
    const float* age         = (const float*)d_in[1];
    const float* targets_age = (const float*)d_in[2];
    const int*   targets     = (const int*)d_in[3];
    const float* W1          = (const float*)d_in[4];
    const float* W2          = (const float*)d_in[5];
    const int*   task_tokens = (const int*)d_in[6];
    const float* time_bins   = (const float*)d_in[7];
    float* out = (float*)d_out;

    char* ws = (char*)d_ws;
    int*      mt       = (int*)(ws + 0);
    int*      firstocc = (int*)(ws + 32768);
    short*    W1t      = (short*)(ws + 65536);
    short*    W2t      = (short*)(ws + 458752);
    float*    partials = (float*)(ws + 462848);
    unsigned* cnt      = (unsigned*)(ws + 464896);

    hipLaunchKernelGGL(k_prep, dim3(81), dim3(256), 0, stream,
                       task_tokens, W1, W2, targets, W1t, W2t, mt, firstocc, cnt);
    hipLaunchKernelGGL(k_main, dim3(GRID_MAIN_), dim3(512), 0, stream,
                       h, age, targets_age, mt, firstocc, W1t, W2t, time_bins,
                       partials, cnt, out);
}

// Round 10
// 40.583 us; speedup vs baseline: 1.3213x; 1.3213x over previous
//
#include <hip/hip_runtime.h>
#include <hip/hip_bf16.h>

#define B_      4
#define L_      2048
#define NE_     768
#define NOUT_   256     // N_BINS * N_HIDDEN
#define NH_     32
#define NB_     8
#define V_      64
#define VOCAB_  1270
#define NC_     32          // chunks per batch row
#define CS_     64          // L_/NC_
#define BM_     32
#define BK_     32
#define NT_     24          // NE_/BK_
#define NROWS_  8192
#define GRID_MAIN_ 256
#define INV_M_  (1.0f / 4194304.0f) // 1/(B*L*NB*V)
#define INF_    0x7FFFFFFF

typedef float f32x4 __attribute__((ext_vector_type(4)));
typedef short s16x8 __attribute__((ext_vector_type(8)));

__device__ __forceinline__ unsigned short f2bf(float x) {
    union { float f; unsigned u; } c; c.f = x;
    unsigned u = c.u;
    return (unsigned short)((u + 0x7fffu + ((u >> 16) & 1u)) >> 16);   // RNE
}

__device__ __forceinline__ void glds16(const short* g, short* l) {
    __builtin_amdgcn_global_load_lds(
        (const __attribute__((address_space(1))) unsigned int*)(const void*)g,
        (__attribute__((address_space(3))) unsigned int*)(void*)l,
        16, 0, 0);
}

// ---------------- workspace layout (bytes) ----------------
// [0     , 32768 ) mt        int[B*L]
// [32768 , 65536 ) firstocc  int[B*NC*V]
// [65536 , 458752) W1t       bf16[256][768]
// [458752, 462848) W2t       bf16[64][32]
// [462848, 464896) partials  float[512] (256 used)
// [464896, 464900) cnt       unsigned

// ---- kernel 1: blocks 0..47 W1t transpose; block 48 W2t + cnt reset;
//                blocks 49..80 mt + firstocc (4 chunks per block)
__global__ void __launch_bounds__(256)
k_prep(const int* __restrict__ task_tokens, const float* __restrict__ W1,
       const float* __restrict__ W2, const int* __restrict__ targets,
       short* __restrict__ W1t, short* __restrict__ W2t,
       int* __restrict__ mt, int* __restrict__ firstocc, unsigned* __restrict__ cnt) {
    __shared__ float tl[64][67];
    __shared__ int   stask[V_];
    __shared__ int   smt[4][CS_];
    const int tid = threadIdx.x;

    if (blockIdx.x < 48) {
        const int tIdx = blockIdx.x;
        const int kt = (tIdx % 12) * 64;
        const int ct = (tIdx / 12) * 64;
        #pragma unroll
        for (int p = 0; p < 4; ++p) {
            int kk = (tid >> 4) + p * 16;
            int cc = (tid & 15) * 4;
            float4 v = *reinterpret_cast<const float4*>(&W1[(kt + kk) * NOUT_ + ct + cc]);
            tl[kk][cc] = v.x; tl[kk][cc + 1] = v.y; tl[kk][cc + 2] = v.z; tl[kk][cc + 3] = v.w;
        }
        __syncthreads();
        #pragma unroll
        for (int p = 0; p < 8; ++p) {
            int oc  = (tid >> 5) + p * 8;
            int ok2 = (tid & 31) * 2;
            unsigned pk = ((unsigned)f2bf(tl[ok2 + 1][oc]) << 16) | f2bf(tl[ok2][oc]);
            *reinterpret_cast<unsigned*>(&W1t[(ct + oc) * NE_ + kt + ok2]) = pk;
        }
        return;
    }
    if (blockIdx.x == 48) {
        if (tid == 0) cnt[0] = 0u;
        #pragma unroll
        for (int q = 0; q < 8; ++q) {
            int i = tid + q * 256;
            int col = i >> 5, j = i & 31;
            W2t[col * NH_ + j] = (short)f2bf(W2[j * V_ + col]);
        }
        return;
    }
    // ---- occ blocks: 4 chunks each ----
    if (tid < V_) stask[tid] = task_tokens[tid];
    __syncthreads();
    const int gi = tid >> 6;
    const int v  = tid & 63;
    const int g  = (blockIdx.x - 49) * 4 + gi;
    const int b  = g >> 5, c = g & 31;
    int t = targets[b * L_ + c * CS_ + v];
    int mval = -1;
    #pragma unroll
    for (int j = 0; j < V_; ++j)
        mval = (stask[j] == t) ? j : mval;
    mt[b * L_ + c * CS_ + v] = mval;
    smt[gi][v] = mval;                          // wave-local
    int first = INF_;
    for (int j = CS_ - 1; j >= 0; --j)
        if (smt[gi][j] == v) first = c * CS_ + j;
    firstocc[(b * NC_ + c) * V_ + v] = first;
}

// ---- kernel 2: fused tte + glds/counted-vmcnt pipelined bf16 MFMA GEMM1(32x256)
//                + MFMA GEMM2 + loss + last-block final reduce
__global__ void __launch_bounds__(512, 2)
k_main(const float* __restrict__ h, const float* __restrict__ age,
       const float* __restrict__ targets_age,
       const int* __restrict__ mt, const int* __restrict__ firstocc,
       const short* __restrict__ W1t, const short* __restrict__ W2t,
       const float* __restrict__ time_bins, float* __restrict__ partials,
       unsigned* __restrict__ cnt, float* __restrict__ out) {
    // B tiles: 4 buffers, chunk-major [buf][kchunk][row][8]  (64 KB, glds dest)
    __shared__ __align__(16) short sB[4][4][256][8];
    __shared__ __align__(16) short sA[2][BM_][40];
    __shared__ __align__(16) short sW2[V_][40];
    __shared__ float stte[BM_][66];
    __shared__ int   sminI[8][V_];
    __shared__ int   smt[CS_];
    __shared__ float sage[BM_];
    __shared__ float sred[8];
    __shared__ float s2[4];
    __shared__ int   sLast;

    const int tid = threadIdx.x;
    const int w   = tid >> 6;
    const int l   = tid & 63;
    const int l15 = l & 15;
    const int l4  = l >> 4;
    const int r0  = blockIdx.x * BM_;
    const int b   = r0 >> 11;
    const int pos0 = r0 & (L_ - 1);
    const int c    = pos0 >> 6;           // chunk
    const int off  = pos0 & 63;           // 0 or 32

    // ---- staging geometry ----
    const int arow = tid >> 4;            // 0..31
    const int akc  = tid & 15;            // float2 chunk
    const float* hA = &h[(r0 + arow) * NE_ + akc * 2];
    // per-wave glds segments: s = w*2+i -> kchunk c_i, rowblock rb_i
    const int c0  = (w * 2) >> 2,     rb0 = (w * 2) & 3;
    const int c1  = (w * 2 + 1) >> 2, rb1 = (w * 2 + 1) & 3;
    const short* gB0 = &W1t[(rb0 * 64 + l) * NE_ + c0 * 8];
    const short* gB1 = &W1t[(rb1 * 64 + l) * NE_ + c1 * 8];

#define GLDS_TILE(T) { \
    glds16(gB0 + (T) * BK_, &sB[(T) & 3][c0][rb0 * 64][0]); \
    glds16(gB1 + (T) * BK_, &sB[(T) & 3][c1][rb1 * 64][0]); }

    // ---- prologue: issue stages 0..2 + A slots 0..3 ----
    GLDS_TILE(0); GLDS_TILE(1); GLDS_TILE(2);
    float2 aR[4];
    aR[0] = *(const float2*)(hA + 0 * BK_);
    aR[1] = *(const float2*)(hA + 1 * BK_);
    aR[2] = *(const float2*)(hA + 2 * BK_);
    aR[3] = *(const float2*)(hA + 3 * BK_);

    // ---- stage small stuff ----
    if (tid < CS_)  smt[tid]  = mt[b * L_ + c * CS_ + tid];
    if (tid < BM_)  sage[tid] = age[r0 + tid];
    if (tid < 256) {
        int col = tid >> 2, ch = tid & 3;
        *(s16x8*)&sW2[col][ch * 8] = *(const s16x8*)&W2t[col * NH_ + ch * 8];
    }

    // ---- wave-parallel suffix-min over later chunks ----
    {
        int cur = INF_;
        #pragma unroll
        for (int k = 0; k < 4; ++k) {
            int cc = c + 1 + w + k * 8;
            if (cc < NC_) cur = min(cur, firstocc[(b * NC_ + cc) * V_ + l]);
        }
        sminI[w][l] = cur;
    }
    __syncthreads();

    // ---- inline tte scan (wave w owns rows w*4..w*4+3) ----
    {
        const int v  = l;
        const int rg = w;
        int cur = INF_;
        #pragma unroll
        for (int ww = 0; ww < 8; ++ww) cur = min(cur, sminI[ww][v]);
        int* stteI = (int*)stte;
        const int jmin = off + rg * 4;
        for (int j = CS_ - 1; j >= jmin; --j) {
            if (smt[j] == v) cur = c * CS_ + j;
            int br = j - off;
            if ((br >> 2) == rg) stteI[br * 66 + v] = cur;
        }
        #pragma unroll
        for (int jr = 0; jr < 4; ++jr) {
            int br  = rg * 4 + jr;
            int tok = stteI[br * 66 + v];
            float val = -1.0f;
            if (tok != INF_) val = targets_age[b * L_ + tok] - sage[br];
            stte[br][v] = val;
        }
    }

    // ---- write A tile 0, full barrier (drains prologue stages too) ----
    {
        unsigned pk = ((unsigned)f2bf(aR[0].y) << 16) | f2bf(aR[0].x);
        *(unsigned*)&sA[0][arow][akc * 2] = pk;
    }
    __syncthreads();

    // ---- K loop: stage(t+3) via glds, A(t+4) into reg slot, counted vmcnt ----
    f32x4 acc00 = {}, acc01 = {}, acc10 = {}, acc11 = {};

#define KSTEP(T, VN) { \
    if ((T) + 3 < NT_) { GLDS_TILE((T) + 3); } \
    if ((T) + 4 < NT_) aR[((T) + 4) & 3] = *(const float2*)(hA + ((T) + 4) * BK_); \
    if ((T) + 1 < NT_) { \
        const float2 av = aR[((T) + 1) & 3]; \
        unsigned pk = ((unsigned)f2bf(av.y) << 16) | f2bf(av.x); \
        *(unsigned*)&sA[((T) + 1) & 1][arow][akc * 2] = pk; \
    } \
    { \
        s16x8 af0 = *(const s16x8*)&sA[(T) & 1][l15][l4 * 8]; \
        s16x8 af1 = *(const s16x8*)&sA[(T) & 1][16 + l15][l4 * 8]; \
        s16x8 bf0 = *(const s16x8*)&sB[(T) & 3][l4][w * 32 + l15][0]; \
        s16x8 bf1 = *(const s16x8*)&sB[(T) & 3][l4][w * 32 + 16 + l15][0]; \
        acc00 = __builtin_amdgcn_mfma_f32_16x16x32_bf16(af0, bf0, acc00, 0, 0, 0); \
        acc01 = __builtin_amdgcn_mfma_f32_16x16x32_bf16(af0, bf1, acc01, 0, 0, 0); \
        acc10 = __builtin_amdgcn_mfma_f32_16x16x32_bf16(af1, bf0, acc10, 0, 0, 0); \
        acc11 = __builtin_amdgcn_mfma_f32_16x16x32_bf16(af1, bf1, acc11, 0, 0, 0); \
    } \
    asm volatile("s_waitcnt vmcnt(" #VN ") lgkmcnt(0)" ::: "memory"); \
    __builtin_amdgcn_s_barrier(); \
    asm volatile("" ::: "memory"); }

    KSTEP(0, 7)  KSTEP(1, 7)  KSTEP(2, 7)  KSTEP(3, 7)
    KSTEP(4, 7)  KSTEP(5, 7)  KSTEP(6, 7)  KSTEP(7, 7)
    KSTEP(8, 7)  KSTEP(9, 7)  KSTEP(10, 7) KSTEP(11, 7)
    KSTEP(12, 7) KSTEP(13, 7) KSTEP(14, 7) KSTEP(15, 7)
    KSTEP(16, 7) KSTEP(17, 7) KSTEP(18, 7) KSTEP(19, 7)
    KSTEP(20, 6) KSTEP(21, 3) KSTEP(22, 0)
    // last tile: no staging, no barrier needed before the syncthreads below
    {
        s16x8 af0 = *(const s16x8*)&sA[23 & 1][l15][l4 * 8];
        s16x8 af1 = *(const s16x8*)&sA[23 & 1][16 + l15][l4 * 8];
        s16x8 bf0 = *(const s16x8*)&sB[23 & 3][l4][w * 32 + l15][0];
        s16x8 bf1 = *(const s16x8*)&sB[23 & 3][l4][w * 32 + 16 + l15][0];
        acc00 = __builtin_amdgcn_mfma_f32_16x16x32_bf16(af0, bf0, acc00, 0, 0, 0);
        acc01 = __builtin_amdgcn_mfma_f32_16x16x32_bf16(af0, bf1, acc01, 0, 0, 0);
        acc10 = __builtin_amdgcn_mfma_f32_16x16x32_bf16(af1, bf0, acc10, 0, 0, 0);
        acc11 = __builtin_amdgcn_mfma_f32_16x16x32_bf16(af1, bf1, acc11, 0, 0, 0);
    }
    __syncthreads();      // all reads of sB done before sH overlay

    // ---- hh -> sH (overlaying sB); wave w owns bin n = w ----
    short (*sH)[BM_][40] = (short (*)[BM_][40])&sB[0][0][0][0];
    {
        f32x4 a0v = acc00, a1v = acc01, a2v = acc10, a3v = acc11;
        #pragma unroll
        for (int jr = 0; jr < 4; ++jr) {
            sH[w][l4 * 4 + jr][l15]          = (short)f2bf(a0v[jr]);
            sH[w][l4 * 4 + jr][16 + l15]     = (short)f2bf(a1v[jr]);
            sH[w][16 + l4 * 4 + jr][l15]     = (short)f2bf(a2v[jr]);
            sH[w][16 + l4 * 4 + jr][16 + l15]= (short)f2bf(a3v[jr]);
        }
    }
    __syncthreads();

    // ---- GEMM2 + loss: wave owns (rf = w&1, cf = w>>1), loops all 8 bins ----
    const int rf = w & 1;
    const int cf = w >> 1;
    const int v  = cf * 16 + l15;
    s16x8 b2 = *(const s16x8*)&sW2[v][l4 * 8];

    float tb[NB_ + 1];
    #pragma unroll
    for (int n = 0; n <= NB_; ++n) tb[n] = time_bins[n];

    float tva[4], lcv[4];
    const float lastTA = targets_age[b * L_ + (L_ - 1)];
    #pragma unroll
    for (int jr = 0; jr < 4; ++jr) {
        int br = rf * 16 + l4 * 4 + jr;
        tva[jr] = stte[br][v];
        lcv[jr] = lastTA - sage[br];
    }

    float part = 0.0f;
    const f32x4 zero = {};
    #pragma unroll
    for (int n = 0; n < NB_; ++n) {
        s16x8 a2 = *(const s16x8*)&sH[n][rf * 16 + l15][l4 * 8];
        f32x4 c2 = __builtin_amdgcn_mfma_f32_16x16x32_bf16(a2, b2, zero, 0, 0, 0);
        float sn = tb[n], en = tb[n + 1], wn = en - sn;
        #pragma unroll
        for (int jr = 0; jr < 4; ++jr) {
            float ll = c2[jr];
            float ex = __expf(ll);
            float tv = tva[jr];
            bool occ = (tv > sn) && (tv <= en);
            float cn = fminf(fmaxf(lcv[jr], 0.0f), wn);
            part += ex * (occ ? tv : cn) - (occ ? ll : 0.0f);
        }
    }

    #pragma unroll
    for (int offs = 32; offs > 0; offs >>= 1) part += __shfl_xor(part, offs);
    if (l == 0) sred[w] = part;
    __syncthreads();
    if (tid == 0) {
        float s = 0.0f;
        #pragma unroll
        for (int i = 0; i < 8; ++i) s += sred[i];
        __hip_atomic_store(&partials[blockIdx.x], s, __ATOMIC_RELEASE, __HIP_MEMORY_SCOPE_AGENT);
        unsigned old = __hip_atomic_fetch_add(cnt, 1u, __ATOMIC_ACQ_REL, __HIP_MEMORY_SCOPE_AGENT);
        sLast = (old == GRID_MAIN_ - 1u);
    }
    __syncthreads();
    if (sLast) {
        float x = 0.0f;
        if (tid < 256)
            x = __hip_atomic_load(&partials[tid], __ATOMIC_RELAXED, __HIP_MEMORY_SCOPE_AGENT);
        #pragma unroll
        for (int o = 32; o > 0; o >>= 1) x += __shfl_xor(x, o);
        if (tid < 256 && (tid & 63) == 0) s2[tid >> 6] = x;
        __syncthreads();
        if (tid == 0) out[0] = (s2[0] + s2[1] + s2[2] + s2[3]) * INV_M_;
    }
}

extern "C" void kernel_launch(void* const* d_in, const int* in_sizes, int n_in,
                              void* d_out, int out_size, void* d_ws, size_t ws_size,
                              hipStream_t stream) {
    const float* h           = (const float*)d_in[0];
    const float* age         = (const float*)d_in[1];
    const float* targets_age = (const float*)d_in[2];
    const int*   targets     = (const int*)d_in[3];
    const float* W1          = (const float*)d_in[4];
    const float* W2          = (const float*)d_in[5];
    const int*   task_tokens = (const int*)d_in[6];
    const float* time_bins   = (const float*)d_in[7];
    float* out = (float*)d_out;

    char* ws = (char*)d_ws;
    int*      mt       = (int*)(ws + 0);
    int*      firstocc = (int*)(ws + 32768);
    short*    W1t      = (short*)(ws + 65536);
    short*    W2t      = (short*)(ws + 458752);
    float*    partials = (float*)(ws + 462848);
    unsigned* cnt      = (unsigned*)(ws + 464896);

    hipLaunchKernelGGL(k_prep, dim3(81), dim3(256), 0, stream,
                       task_tokens, W1, W2, targets, W1t, W2t, mt, firstocc, cnt);
    hipLaunchKernelGGL(k_main, dim3(GRID_MAIN_), dim3(512), 0, stream,
                       h, age, targets_age, mt, firstocc, W1t, W2t, time_bins,
                       partials, cnt, out);
}

// Round 11
// 36.462 us; speedup vs baseline: 1.4706x; 1.1130x over previous
//
#include <hip/hip_runtime.h>
#include <hip/hip_bf16.h>

#define B_      4
#define L_      2048
#define NE_     768
#define NOUT_   256     // N_BINS * N_HIDDEN
#define NH_     32
#define NB_     8
#define V_      64
#define VOCAB_  1270
#define NC_     32          // chunks per batch row
#define CS_     64          // L_/NC_
#define BM_     32
#define BK_     32
#define NT_     24          // NE_/BK_
#define NROWS_  8192
#define GRID_MAIN_ 256
#define INV_M_  (1.0f / 4194304.0f) // 1/(B*L*NB*V)
#define INF_    0x7FFFFFFF

typedef float f32x4 __attribute__((ext_vector_type(4)));
typedef short s16x8 __attribute__((ext_vector_type(8)));

__device__ __forceinline__ unsigned short f2bf(float x) {
    union { float f; unsigned u; } c; c.f = x;
    unsigned u = c.u;
    return (unsigned short)((u + 0x7fffu + ((u >> 16) & 1u)) >> 16);   // RNE
}

__device__ __forceinline__ s16x8 cvt8(float4 a, float4 b) {
    union { __hip_bfloat162 h2[4]; s16x8 v; } r;
    r.h2[0] = __float22bfloat162_rn(make_float2(a.x, a.y));
    r.h2[1] = __float22bfloat162_rn(make_float2(a.z, a.w));
    r.h2[2] = __float22bfloat162_rn(make_float2(b.x, b.y));
    r.h2[3] = __float22bfloat162_rn(make_float2(b.z, b.w));
    return r.v;
}

__device__ __forceinline__ void glds16(const short* g, short* l) {
    __builtin_amdgcn_global_load_lds(
        (const __attribute__((address_space(1))) unsigned int*)(const void*)g,
        (__attribute__((address_space(3))) unsigned int*)(void*)l,
        16, 0, 0);
}

// ---------------- workspace layout (bytes) ----------------
// [0     , 32768 ) mt        int[B*L]
// [32768 , 65536 ) firstocc  int[B*NC*V]
// [65536 , 458752) W1t       bf16[256][768]
// [458752, 462848) W2t       bf16[64][32]
// [462848, 464896) partials  float[512] (256 used)
// [464896, 464900) cnt       unsigned

// ---- kernel 1: blocks 0..47 W1t transpose; block 48 W2t + cnt reset;
//                blocks 49..80 mt + firstocc (4 chunks per block)
__global__ void __launch_bounds__(256)
k_prep(const int* __restrict__ task_tokens, const float* __restrict__ W1,
       const float* __restrict__ W2, const int* __restrict__ targets,
       short* __restrict__ W1t, short* __restrict__ W2t,
       int* __restrict__ mt, int* __restrict__ firstocc, unsigned* __restrict__ cnt) {
    __shared__ float tl[64][67];
    __shared__ int   stask[V_];
    __shared__ int   smt[4][CS_];
    const int tid = threadIdx.x;

    if (blockIdx.x < 48) {
        const int tIdx = blockIdx.x;
        const int kt = (tIdx % 12) * 64;
        const int ct = (tIdx / 12) * 64;
        #pragma unroll
        for (int p = 0; p < 4; ++p) {
            int kk = (tid >> 4) + p * 16;
            int cc = (tid & 15) * 4;
            float4 v = *reinterpret_cast<const float4*>(&W1[(kt + kk) * NOUT_ + ct + cc]);
            tl[kk][cc] = v.x; tl[kk][cc + 1] = v.y; tl[kk][cc + 2] = v.z; tl[kk][cc + 3] = v.w;
        }
        __syncthreads();
        #pragma unroll
        for (int p = 0; p < 8; ++p) {
            int oc  = (tid >> 5) + p * 8;
            int ok2 = (tid & 31) * 2;
            unsigned pk = ((unsigned)f2bf(tl[ok2 + 1][oc]) << 16) | f2bf(tl[ok2][oc]);
            *reinterpret_cast<unsigned*>(&W1t[(ct + oc) * NE_ + kt + ok2]) = pk;
        }
        return;
    }
    if (blockIdx.x == 48) {
        if (tid == 0) cnt[0] = 0u;
        #pragma unroll
        for (int q = 0; q < 8; ++q) {
            int i = tid + q * 256;
            int col = i >> 5, j = i & 31;
            W2t[col * NH_ + j] = (short)f2bf(W2[j * V_ + col]);
        }
        return;
    }
    // ---- occ blocks: 4 chunks each ----
    if (tid < V_) stask[tid] = task_tokens[tid];
    __syncthreads();
    const int gi = tid >> 6;
    const int v  = tid & 63;
    const int g  = (blockIdx.x - 49) * 4 + gi;
    const int b  = g >> 5, c = g & 31;
    int t = targets[b * L_ + c * CS_ + v];
    int mval = -1;
    #pragma unroll
    for (int j = 0; j < V_; ++j)
        mval = (stask[j] == t) ? j : mval;
    mt[b * L_ + c * CS_ + v] = mval;
    smt[gi][v] = mval;                          // wave-local
    int first = INF_;
    for (int j = CS_ - 1; j >= 0; --j)
        if (smt[gi][j] == v) first = c * CS_ + j;
    firstocc[(b * NC_ + c) * V_ + v] = first;
}

// ---- kernel 2: fused tte + barrier-free wave-private bf16 MFMA GEMM1(32x256)
//                + MFMA GEMM2 + loss + last-block final reduce
__global__ void __launch_bounds__(512)
k_main(const float* __restrict__ h, const float* __restrict__ age,
       const float* __restrict__ targets_age,
       const int* __restrict__ mt, const int* __restrict__ firstocc,
       const short* __restrict__ W1t, const short* __restrict__ W2t,
       const float* __restrict__ time_bins, float* __restrict__ partials,
       unsigned* __restrict__ cnt, float* __restrict__ out) {
    // A tile: full K, bf16, staged once. padded 776 -> 2-way banks on frag reads
    __shared__ __align__(16) short sA[BM_][776];         // 49.7 KB (reused as sH)
    // B ring: wave-private [wave][buf][half][kchunk][row16][8]   64 KB
    __shared__ __align__(16) short sB[8][4][2][4][16][8];
    __shared__ __align__(16) short sW2[V_][40];
    __shared__ float stte[BM_][66];
    __shared__ int   sminI[8][V_];
    __shared__ int   smt[CS_];
    __shared__ float sage[BM_];
    __shared__ float sred[8];
    __shared__ float s2[4];
    __shared__ int   sLast;

    const int tid = threadIdx.x;
    const int w   = tid >> 6;
    const int l   = tid & 63;
    const int l15 = l & 15;
    const int l4  = l >> 4;
    const int kb  = l4 * 8;
    const int r0  = blockIdx.x * BM_;
    const int b   = r0 >> 11;
    const int pos0 = r0 & (L_ - 1);
    const int c    = pos0 >> 6;           // chunk
    const int off  = pos0 & 63;           // 0 or 32

    // ---- wave-private B staging pointers ----
    short* sbw = &sB[w][0][0][0][0][0];                 // 4096 shorts per wave
    const short* gB0 = &W1t[(w * 32 + l15) * NE_ + kb]; // half 0 rows
    const short* gB1 = gB0 + 16 * NE_;                  // half 1 rows

#define GLDS_TILE(T) { \
    glds16(gB0 + (T) * BK_, sbw + ((T) & 3) * 1024); \
    glds16(gB1 + (T) * BK_, sbw + ((T) & 3) * 1024 + 512); }

    // ---- stage small stuff ----
    if (tid < CS_)  smt[tid]  = mt[b * L_ + c * CS_ + tid];
    if (tid < BM_)  sage[tid] = age[r0 + tid];
    if (tid < 256) {
        int col = tid >> 2, ch = tid & 3;
        *(s16x8*)&sW2[col][ch * 8] = *(const s16x8*)&W2t[col * NH_ + ch * 8];
    }

    // ---- stage full A tile (fp32 -> bf16), coalesced 512B per 16-lane group ----
    {
        const int row = tid >> 4;
        const float* hrow = &h[(r0 + row) * NE_];
        #pragma unroll
        for (int q = 0; q < 6; ++q) {
            int col = (tid & 15) * 8 + q * 128;
            float4 x0 = *(const float4*)&hrow[col];
            float4 x1 = *(const float4*)&hrow[col + 4];
            *(s16x8*)&sA[row][col] = cvt8(x0, x1);
        }
    }

    // ---- wave-parallel suffix-min over later chunks ----
    {
        int cur = INF_;
        #pragma unroll
        for (int k = 0; k < 4; ++k) {
            int cc = c + 1 + w + k * 8;
            if (cc < NC_) cur = min(cur, firstocc[(b * NC_ + cc) * V_ + l]);
        }
        sminI[w][l] = cur;
    }
    __syncthreads();

    // ---- inline tte scan (wave w owns rows w*4..w*4+3) ----
    {
        const int v  = l;
        const int rg = w;
        int cur = INF_;
        #pragma unroll
        for (int ww = 0; ww < 8; ++ww) cur = min(cur, sminI[ww][v]);
        int* stteI = (int*)stte;
        const int jmin = off + rg * 4;
        for (int j = CS_ - 1; j >= jmin; --j) {
            if (smt[j] == v) cur = c * CS_ + j;
            int br = j - off;
            if ((br >> 2) == rg) stteI[br * 66 + v] = cur;
        }
        #pragma unroll
        for (int jr = 0; jr < 4; ++jr) {
            int br  = rg * 4 + jr;
            int tok = stteI[br * 66 + v];
            float val = -1.0f;
            if (tok != INF_) val = targets_age[b * L_ + tok] - sage[br];
            stte[br][v] = val;
        }
    }
    __syncthreads();        // sA fully staged; drains all prologue vm/lgkm counts

    // ---- prefetch B tiles 0..3 into the wave-private ring ----
    GLDS_TILE(0) GLDS_TILE(1) GLDS_TILE(2) GLDS_TILE(3)

    // ---- K loop: NO barriers. per-wave counted vmcnt; glds ring depth 4 ----
    f32x4 acc00 = {}, acc01 = {}, acc10 = {}, acc11 = {};

#define KSTEP(T, VN) { \
    asm volatile("s_waitcnt vmcnt(" #VN ")" ::: "memory"); \
    s16x8 af0 = *(const s16x8*)&sA[l15][(T) * BK_ + kb]; \
    s16x8 af1 = *(const s16x8*)&sA[16 + l15][(T) * BK_ + kb]; \
    s16x8 bf0 = *(const s16x8*)(sbw + ((T) & 3) * 1024 + l4 * 128 + l15 * 8); \
    s16x8 bf1 = *(const s16x8*)(sbw + ((T) & 3) * 1024 + 512 + l4 * 128 + l15 * 8); \
    asm volatile("s_waitcnt lgkmcnt(0)" ::: "memory"); \
    __builtin_amdgcn_sched_barrier(0); \
    if ((T) + 4 < NT_) { GLDS_TILE((T) + 4) } \
    acc00 = __builtin_amdgcn_mfma_f32_16x16x32_bf16(af0, bf0, acc00, 0, 0, 0); \
    acc01 = __builtin_amdgcn_mfma_f32_16x16x32_bf16(af0, bf1, acc01, 0, 0, 0); \
    acc10 = __builtin_amdgcn_mfma_f32_16x16x32_bf16(af1, bf0, acc10, 0, 0, 0); \
    acc11 = __builtin_amdgcn_mfma_f32_16x16x32_bf16(af1, bf1, acc11, 0, 0, 0); }

    KSTEP(0, 6)  KSTEP(1, 6)  KSTEP(2, 6)  KSTEP(3, 6)
    KSTEP(4, 6)  KSTEP(5, 6)  KSTEP(6, 6)  KSTEP(7, 6)
    KSTEP(8, 6)  KSTEP(9, 6)  KSTEP(10, 6) KSTEP(11, 6)
    KSTEP(12, 6) KSTEP(13, 6) KSTEP(14, 6) KSTEP(15, 6)
    KSTEP(16, 6) KSTEP(17, 6) KSTEP(18, 6) KSTEP(19, 6)
    KSTEP(20, 6) KSTEP(21, 4) KSTEP(22, 2) KSTEP(23, 0)

    __syncthreads();        // all waves done with sA/sB; safe to overlay sH

    // ---- hh -> sH (overlaying sA); wave w owns bin n = w ----
    short (*sH)[BM_][40] = (short (*)[BM_][40])&sA[0][0];
    #pragma unroll
    for (int jr = 0; jr < 4; ++jr) {
        sH[w][l4 * 4 + jr][l15]            = (short)f2bf(acc00[jr]);
        sH[w][l4 * 4 + jr][16 + l15]       = (short)f2bf(acc01[jr]);
        sH[w][16 + l4 * 4 + jr][l15]       = (short)f2bf(acc10[jr]);
        sH[w][16 + l4 * 4 + jr][16 + l15]  = (short)f2bf(acc11[jr]);
    }
    __syncthreads();

    // ---- GEMM2 + loss: wave owns (rf = w&1, cf = w>>1), loops all 8 bins ----
    const int rf = w & 1;
    const int cf = w >> 1;
    const int v  = cf * 16 + l15;
    s16x8 b2 = *(const s16x8*)&sW2[v][l4 * 8];

    float tb[NB_ + 1];
    #pragma unroll
    for (int n = 0; n <= NB_; ++n) tb[n] = time_bins[n];

    float tva[4], lcv[4];
    const float lastTA = targets_age[b * L_ + (L_ - 1)];
    #pragma unroll
    for (int jr = 0; jr < 4; ++jr) {
        int br = rf * 16 + l4 * 4 + jr;
        tva[jr] = stte[br][v];
        lcv[jr] = lastTA - sage[br];
    }

    float part = 0.0f;
    const f32x4 zero = {};
    #pragma unroll
    for (int n = 0; n < NB_; ++n) {
        s16x8 a2 = *(const s16x8*)&sH[n][rf * 16 + l15][l4 * 8];
        f32x4 c2 = __builtin_amdgcn_mfma_f32_16x16x32_bf16(a2, b2, zero, 0, 0, 0);
        float sn = tb[n], en = tb[n + 1], wn = en - sn;
        #pragma unroll
        for (int jr = 0; jr < 4; ++jr) {
            float ll = c2[jr];
            float ex = __expf(ll);
            float tv = tva[jr];
            bool occ = (tv > sn) && (tv <= en);
            float cn = fminf(fmaxf(lcv[jr], 0.0f), wn);
            part += ex * (occ ? tv : cn) - (occ ? ll : 0.0f);
        }
    }

    #pragma unroll
    for (int offs = 32; offs > 0; offs >>= 1) part += __shfl_xor(part, offs);
    if (l == 0) sred[w] = part;
    __syncthreads();
    if (tid == 0) {
        float s = 0.0f;
        #pragma unroll
        for (int i = 0; i < 8; ++i) s += sred[i];
        __hip_atomic_store(&partials[blockIdx.x], s, __ATOMIC_RELEASE, __HIP_MEMORY_SCOPE_AGENT);
        unsigned old = __hip_atomic_fetch_add(cnt, 1u, __ATOMIC_ACQ_REL, __HIP_MEMORY_SCOPE_AGENT);
        sLast = (old == GRID_MAIN_ - 1u);
    }
    __syncthreads();
    if (sLast) {
        float x = 0.0f;
        if (tid < 256)
            x = __hip_atomic_load(&partials[tid], __ATOMIC_RELAXED, __HIP_MEMORY_SCOPE_AGENT);
        #pragma unroll
        for (int o = 32; o > 0; o >>= 1) x += __shfl_xor(x, o);
        if (tid < 256 && (tid & 63) == 0) s2[tid >> 6] = x;
        __syncthreads();
        if (tid == 0) out[0] = (s2[0] + s2[1] + s2[2] + s2[3]) * INV_M_;
    }
}

extern "C" void kernel_launch(void* const* d_in, const int* in_sizes, int n_in,
                              void* d_out, int out_size, void* d_ws, size_t ws_size,
                              hipStream_t stream) {
    const float* h           = (const float*)d_in[0];
    const float* age         = (const float*)d_in[1];
    const float* targets_age = (const float*)d_in[2];
    const int*   targets     = (const int*)d_in[3];
    const float* W1          = (const float*)d_in[4];
    const float* W2          = (const float*)d_in[5];
    const int*   task_tokens = (const int*)d_in[6];
    const float* time_bins   = (const float*)d_in[7];
    float* out = (float*)d_out;

    char* ws = (char*)d_ws;
    int*      mt       = (int*)(ws + 0);
    int*      firstocc = (int*)(ws + 32768);
    short*    W1t      = (short*)(ws + 65536);
    short*    W2t      = (short*)(ws + 458752);
    float*    partials = (float*)(ws + 462848);
    unsigned* cnt      = (unsigned*)(ws + 464896);

    hipLaunchKernelGGL(k_prep, dim3(81), dim3(256), 0, stream,
                       task_tokens, W1, W2, targets, W1t, W2t, mt, firstocc, cnt);
    hipLaunchKernelGGL(k_main, dim3(GRID_MAIN_), dim3(512), 0, stream,
                       h, age, targets_age, mt, firstocc, W1t, W2t, time_bins,
                       partials, cnt, out);
}